// Round 9
// baseline (369.819 us; speedup 1.0000x reference)
//
#include <hip/hip_runtime.h>
#include <hip/hip_bf16.h>
#include <math.h>

// Problem constants
#define BZ   8
#define DD   512
#define LL   2048
#define HH   8
#define MM   1024
#define DH   64
#define NN   (BZ * LL)               // 16384 rows per head
#define TOTAL_ELEMS (HH * NN * DH)   // 8388608

// d_out layout (floats): [z_q (8388608)] [vq_loss (1)] [indices (131072)] [codebooks (524288)]
#define OFF_ZQ   0
#define OFF_LOSS 8388608
#define OFF_IDX  8388609
#define OFF_CB   8519681

// R18 d_ws layout (sums mode): [sse 64B][cnts 32KB][sums 2MB][cb_hi 1MB][cb_lo 1MB]
#define WS2_SSE   0
#define WS2_CNT   64
#define WS2_SUM   (64 + HH * MM * 4)                          // 32,832
#define WS2_CBHI  (WS2_SUM + HH * MM * DH * 4)                // 2,129,984
#define WS2_CBLO  (WS2_CBHI + HH * MM * DH * 2)               // 3,178,560
#define WS2_NEED  ((size_t)WS2_CBLO + HH * MM * DH * 2)       // 4,227,136

typedef __attribute__((ext_vector_type(8))) short short8;
typedef __attribute__((ext_vector_type(4))) float float4v;

__device__ __forceinline__ unsigned short f2bf(float f) {
    unsigned int u = __builtin_bit_cast(unsigned int, f);
    u += 0x7FFFu + ((u >> 16) & 1u);          // RNE
    return (unsigned short)(u >> 16);
}
__device__ __forceinline__ float bf2f(unsigned short s) {
    unsigned int u = ((unsigned int)s) << 16;
    return __builtin_bit_cast(float, u);
}

__device__ __forceinline__ void gload16(const short* g, short* l) {
    __builtin_amdgcn_global_load_lds(
        (const __attribute__((address_space(1))) unsigned int*)g,
        (__attribute__((address_space(3))) unsigned int*)l, 16, 0, 0);
}

// R18: cvt also zeroes sse + cnts + sums (65536 threads x 8 floats = 2MB sums).
// fp32 codebook -> bf16 hi/lo planes, 16B chunks XOR-swizzled within each
// 128B row (chunk c stored at c^(row&7)) so unpadded LDS tiles read conflict-free.
__global__ __launch_bounds__(256) void cvt_cb_kernel(
    const float* __restrict__ cb, short* __restrict__ hip_, short* __restrict__ lop_,
    float* __restrict__ sse, int* __restrict__ cnts, float* __restrict__ sums)
{
    const int tid = blockIdx.x * 256 + threadIdx.x;
    if (tid < 16) sse[tid] = 0.f;
    if (cnts && tid < HH * MM) cnts[tid] = 0;
    if (sums) {
        const float4 zero = {0.f, 0.f, 0.f, 0.f};
        *(float4*)&sums[tid * 8]     = zero;
        *(float4*)&sums[tid * 8 + 4] = zero;
    }
    const int c   = tid & 7;
    const int row = tid >> 3;                          // h*MM + m
    const float* __restrict__ src = cb + (size_t)row * DH + c * 8;
    short hs[8], ls[8];
#pragma unroll
    for (int j = 0; j < 8; ++j) {
        const float f = src[j];
        const unsigned short hv = f2bf(f);
        hs[j] = (short)hv;
        ls[j] = (short)f2bf(f - bf2f(hv));
    }
    const int dst = row * DH + ((c ^ (row & 7)) * 8);
    *(short8*)&hip_[dst] = *(short8*)hs;
    *(short8*)&lop_[dst] = *(short8*)ls;
}

// R12 assign internals (measured 112us) + R18 epilogue change: instead of
// writing zs (33.5MB) + bucket lists, each lane fire-and-forget atomicAdds its
// 16 zv elements into sums[h][best][k] (64 atomics/row, 8.4M total, no-return
// -> pipelined, fp32 reorder harmless at tolerance). Update then needs no gather.
__global__ __launch_bounds__(512) void vq_assign_kernel(
    const float* __restrict__ z,          // [B, D, L]
    const float* __restrict__ cb,         // [H, M, DH] fp32 (rescreen/epilogue)
    const short* __restrict__ cb_hi,      // bf16 hi, swizzled
    const short* __restrict__ cb_lo,      // bf16 lo, swizzled
    float* __restrict__ zq_out,
    float* __restrict__ idx_out,
    float* __restrict__ sse,
    int*   __restrict__ cnts,             // [H*M] or null
    float* __restrict__ sums)             // [H*M][DH] or null
{
    __shared__ __align__(16) short hi_lds[2][64 * DH];   // 2 x 8 KB
    __shared__ __align__(16) short lo_lds[2][64 * DH];   // 2 x 8 KB
    __shared__ float blk_err[8];

    const int t    = threadIdx.x;
    const int h    = blockIdx.y;
    const int lane = t & 63;
    const int g    = lane >> 4;          // quad 0..3
    const int nloc = lane & 15;
    const int w    = t >> 6;             // wave 0..7

    // This lane's z row (16 rows per wave, 128 per block); 4 quads share a row.
    const int r = blockIdx.x * 128 + w * 16 + nloc;
    const int b = r >> 11;
    const int l = r & (LL - 1);
    const float* __restrict__ zbase = z + ((size_t)(b * DD + h * DH) * LL + l);

    // B-fragment z values: zv[j] <-> k=g*8+j, zv[8+j] <-> k=32+g*8+j.
    float zv[16] __attribute__((aligned(16)));
#pragma unroll
    for (int j = 0; j < 8; ++j) zv[j]     = zbase[(size_t)(g * 8 + j) * LL];
#pragma unroll
    for (int j = 0; j < 8; ++j) zv[8 + j] = zbase[(size_t)(32 + g * 8 + j) * LL];

    short bh[16], bl[16];
#pragma unroll
    for (int j = 0; j < 16; ++j) {
        const unsigned short hv = f2bf(zv[j]);
        bh[j] = (short)hv;
        bl[j] = (short)f2bf(zv[j] - bf2f(hv));
    }
    const short8 Bh0 = *(short8*)&bh[0], Bh1 = *(short8*)&bh[8];
    const short8 Bl0 = *(short8*)&bl[0], Bl1 = *(short8*)&bl[8];

    const short* __restrict__ gh = cb_hi + (size_t)h * MM * DH;
    const short* __restrict__ gl = cb_lo + (size_t)h * MM * DH;

    // Stage one 64-row tile (8 KB hi + 8 KB lo): 512 threads x 16B each plane.
    auto stage = [&](int mt, int buf) {
        const short* sh = gh + (size_t)mt * 64 * DH;
        const short* sl = gl + (size_t)mt * 64 * DH;
        gload16(sh + t * 8, &hi_lds[buf][t * 8]);
        gload16(sl + t * 8, &lo_lds[buf][t * 8]);
    };

    stage(0, 0);

    // 4 independent top-2 chains (one per s class), merged at the end.
    float b1c[4], b2c[4];
    int   i1c[4], i2c[4];
#pragma unroll
    for (int s = 0; s < 4; ++s) { b1c[s] = -1e30f; b2c[s] = -1e30f; i1c[s] = 0; i2c[s] = 0; }

    const int sw8 = nloc & 7;

    for (int mt = 0; mt < MM / 64; ++mt) {
        __syncthreads();                       // vmcnt(0) drains exactly tile mt's DMA
        if (mt + 1 < MM / 64) stage(mt + 1, (mt + 1) & 1);
        const int buf = mt & 1;

#pragma unroll
        for (int s = 0; s < 4; ++s) {
            const short* hrow = &hi_lds[buf][(s * 16 + nloc) * DH];
            const short* lrow = &lo_lds[buf][(s * 16 + nloc) * DH];
            const short8 Ah0 = *(const short8*)&hrow[((g)     ^ sw8) * 8];
            const short8 Ah1 = *(const short8*)&hrow[((g + 4) ^ sw8) * 8];
            const short8 Al0 = *(const short8*)&lrow[((g)     ^ sw8) * 8];
            const short8 Al1 = *(const short8*)&lrow[((g + 4) ^ sw8) * 8];

            float4v acc = {0.f, 0.f, 0.f, 0.f};
            acc = __builtin_amdgcn_mfma_f32_16x16x32_bf16(Ah0, Bh0, acc, 0, 0, 0);
            acc = __builtin_amdgcn_mfma_f32_16x16x32_bf16(Ah1, Bh1, acc, 0, 0, 0);
            acc = __builtin_amdgcn_mfma_f32_16x16x32_bf16(Ah0, Bl0, acc, 0, 0, 0);
            acc = __builtin_amdgcn_mfma_f32_16x16x32_bf16(Ah1, Bl1, acc, 0, 0, 0);
            acc = __builtin_amdgcn_mfma_f32_16x16x32_bf16(Al0, Bh0, acc, 0, 0, 0);
            acc = __builtin_amdgcn_mfma_f32_16x16x32_bf16(Al1, Bh1, acc, 0, 0, 0);

            const int mbase = mt * 64 + s * 16 + g * 4;
#pragma unroll
            for (int reg = 0; reg < 4; ++reg) {
                const float v = acc[reg];
                const int   m = mbase + reg;
                // top-2 of {v, b1, b2}: b1' = max(v,b1); b2' = med3(v,b1,b2).
                const bool gt1 = v > b1c[s];
                const bool gt2 = v > b2c[s];
                b2c[s] = __builtin_amdgcn_fmed3f(v, b1c[s], b2c[s]);
                i2c[s] = gt1 ? i1c[s] : (gt2 ? m : i2c[s]);
                b1c[s] = fmaxf(v, b1c[s]);
                i1c[s] = gt1 ? m : i1c[s];
            }
        }
    }

    // Merge the 4 chains into one top-2 (value desc, index-asc tie-break).
    float b1 = b1c[0], b2 = b2c[0];
    int   i1 = i1c[0], i2 = i2c[0];
#pragma unroll
    for (int s = 1; s < 4; ++s) {
        const float ob1 = b1c[s], ob2 = b2c[s];
        const int   oi1 = i1c[s], oi2 = i2c[s];
        const bool agt = (b1 > ob1) || (b1 == ob1 && i1 < oi1);
        const float w1 = agt ? b1 : ob1;  const int wi1 = agt ? i1 : oi1;
        const float l1 = agt ? ob1 : b1;  const int li1 = agt ? oi1 : i1;
        const float w2 = agt ? b2 : ob2;  const int wi2 = agt ? i2 : oi2;
        const bool sgt = (l1 > w2) || (l1 == w2 && li1 < wi2);
        b1 = w1;  i1 = wi1;
        b2 = sgt ? l1 : w2;  i2 = sgt ? li1 : wi2;
    }

    // Merge top-2 across the 4 quads holding the same row.
#pragma unroll
    for (int off = 16; off <= 32; off <<= 1) {
        float ob1 = __shfl_xor(b1, off, 64);
        int   oi1 = __shfl_xor(i1, off, 64);
        float ob2 = __shfl_xor(b2, off, 64);
        int   oi2 = __shfl_xor(i2, off, 64);
        const bool agt = (b1 > ob1) || (b1 == ob1 && i1 < oi1);
        const float w1  = agt ? b1 : ob1;  const int wi1 = agt ? i1 : oi1;
        const float l1  = agt ? ob1 : b1;  const int li1 = agt ? oi1 : i1;
        const float w2  = agt ? b2 : ob2;  const int wi2 = agt ? i2 : oi2;
        const bool sgt = (l1 > w2) || (l1 == w2 && li1 < wi2);
        b1 = w1;  i1 = wi1;
        b2 = sgt ? l1 : w2;  i2 = sgt ? li1 : wi2;
    }

    // Exact fp64 rescreen of the two candidates (global fp32), reusing zv.
    const float* __restrict__ cbh = cb + (size_t)h * MM * DH;
    const float* __restrict__ c1  = cbh + (size_t)i1 * DH;
    const float* __restrict__ c2  = cbh + (size_t)i2 * DH;
    double d1 = 0.0, d2 = 0.0;
#pragma unroll
    for (int j = 0; j < 8; ++j) {
        const int k0 = g * 8 + j, k1 = 32 + g * 8 + j;
        d1 = fma((double)zv[j],     (double)c1[k0], d1);
        d1 = fma((double)zv[8 + j], (double)c1[k1], d1);
        d2 = fma((double)zv[j],     (double)c2[k0], d2);
        d2 = fma((double)zv[8 + j], (double)c2[k1], d2);
    }
    d1 += __shfl_xor(d1, 16, 64);  d1 += __shfl_xor(d1, 32, 64);
    d2 += __shfl_xor(d2, 16, 64);  d2 += __shfl_xor(d2, 32, 64);
    const int best = (d2 > d1 || (d2 == d1 && i2 < i1)) ? i2 : i1;

    // Epilogue: quantized row, squared error, idx, atomic sums.
    const float* __restrict__ cq  = cbh + (size_t)best * DH;
    float* __restrict__ zqp  = zq_out + ((size_t)(b * DD + h * DH) * LL + l);
    float err = 0.f;
#pragma unroll
    for (int j = 0; j < 8; ++j) {
        const int k0 = g * 8 + j, k1 = 32 + g * 8 + j;
        const float q0 = cq[k0], q1 = cq[k1];
        zqp[(size_t)k0 * LL] = q0;
        zqp[(size_t)k1 * LL] = q1;
        const float e0 = zv[j] - q0, e1 = zv[8 + j] - q1;
        err = fmaf(e0, e0, err);
        err = fmaf(e1, e1, err);
    }
    if (sums) {
        // R18: per-code sum accumulation (fire-and-forget, no-return atomics).
        float* __restrict__ sp = sums + ((size_t)h * MM + best) * DH;
#pragma unroll
        for (int j = 0; j < 8; ++j) {
            atomicAdd(&sp[g * 8 + j],      zv[j]);
            atomicAdd(&sp[32 + g * 8 + j], zv[8 + j]);
        }
    }
    if (g == 0) {
        idx_out[((size_t)b * HH + h) * LL + l] = (float)best;
        if (cnts) atomicAdd(&cnts[h * MM + best], 1);
    }
#pragma unroll
    for (int off = 32; off; off >>= 1) err += __shfl_xor(err, off, 64);
    // Two-stage sse reduction (one atomic per block).
    if (lane == 0) blk_err[w] = err;
    __syncthreads();
    if (t == 0) {
        float s = 0.f;
#pragma unroll
        for (int i = 0; i < 8; ++i) s += blk_err[i];
        atomicAdd(sse, s);
    }
}

// One wave per (h,m) code. R18 fast path: mean = sums[row]/cnt — no gather,
// no list. Scan fallback (cnts==null, thin ws) preserved: rebuild from idx + z.
__global__ __launch_bounds__(256) void vq_update_kernel(
    const float* __restrict__ z,        // [B, D, L]
    const float* __restrict__ cb,       // [H, M, DH]
    const float* __restrict__ idx,      // [B, H, L] as float
    const float* __restrict__ sse,
    float* __restrict__ cb_out,
    float* __restrict__ loss_out,
    const int* __restrict__ cnts,       // [H*M] or null
    const float* __restrict__ sums)     // [H*M][DH] or null
{
    if (blockIdx.x == 0 && threadIdx.x == 0) {
        loss_out[0] = 1.25f * sse[0] / (float)TOTAL_ELEMS;
    }
    const int row  = blockIdx.x * 4 + (threadIdx.x >> 6);   // h*MM + m
    const int lane = threadIdx.x & 63;
    const int h    = row >> 10;
    const int m    = row & (MM - 1);

    float acc = 0.f;
    int   cnt = 0;

    if (cnts) {
        cnt = cnts[row];
        acc = sums[(size_t)row * DH + lane];
    } else {
        const float fm = (float)m;
#pragma unroll 1
        for (int b = 0; b < BZ; ++b) {
            const float* __restrict__ ip = idx + ((size_t)(b * HH + h)) * LL;
            const float* __restrict__ zb = z + ((size_t)(b * DD + h * DH + lane)) * LL;
            float4 cur = *(const float4*)(ip + lane * 4);
#pragma unroll 1
            for (int it = 0; it < LL / 256; ++it) {
                float4 nxt = cur;
                if (it + 1 < LL / 256)
                    nxt = *(const float4*)(ip + (it + 1) * 256 + lane * 4);
#pragma unroll
                for (int j = 0; j < 4; ++j) {
                    const float ivj = (&cur.x)[j];
                    unsigned long long mask = __ballot(ivj == fm);
                    cnt += (int)__popcll(mask);
                    while (mask) {
                        const int src = (int)__ffsll((long long)mask) - 1;
                        mask &= mask - 1;
                        const int l = it * 256 + src * 4 + j;
                        acc += zb[l];
                    }
                }
                cur = nxt;
            }
        }
    }

    const float cf   = (float)cnt;
    const float c    = cb[(size_t)row * DH + lane];
    const float mean = acc / fmaxf(cf, 1.0f);

    float dot = mean * c;
    float nl  = mean * mean;
    float nh  = c * c;
#pragma unroll
    for (int off = 32; off; off >>= 1) {
        dot += __shfl_xor(dot, off, 64);
        nl  += __shfl_xor(nl,  off, 64);
        nh  += __shfl_xor(nh,  off, 64);
    }

    float cosv = dot / fmaxf(sqrtf(nl) * sqrtf(nh), 1e-8f);
    cosv = fminf(fmaxf(cosv, -0.9999999f), 0.9999999f);
    const float omega = acosf(cosv);
    const float so    = sinf(omega);
    float outv = (mean * sinf(0.01f * omega) + c * sinf(0.99f * omega)) / so;

    float ms = outv * outv;
#pragma unroll
    for (int off = 32; off; off >>= 1) ms += __shfl_xor(ms, off, 64);
    ms = ms * (1.0f / (float)DH) + 1.1920929e-07f;
    const float normed = outv / sqrtf(ms);

    cb_out[(size_t)row * DH + lane] = (cnt > 0) ? normed : c;
}

extern "C" void kernel_launch(void* const* d_in, const int* in_sizes, int n_in,
                              void* d_out, int out_size, void* d_ws, size_t ws_size,
                              hipStream_t stream) {
    const float* z  = (const float*)d_in[0];
    const float* cb = (const float*)d_in[1];
    float* out = (float*)d_out;

    const bool sums_mode = ws_size >= WS2_NEED;

    float* sseP  = (float*)d_ws;
    int*   cnts  = sums_mode ? (int*)((char*)d_ws + WS2_CNT) : (int*)0;
    float* sums  = sums_mode ? (float*)((char*)d_ws + WS2_SUM) : (float*)0;
    short* cb_hi = (short*)((char*)d_ws + (sums_mode ? WS2_CBHI : 64));
    short* cb_lo = cb_hi + (size_t)HH * MM * DH;

    // cvt zeroes sse + cnts + sums (no memset node).
    cvt_cb_kernel<<<(HH * MM * DH / 8) / 256, 256, 0, stream>>>(
        cb, cb_hi, cb_lo, sseP, cnts, sums);

    dim3 gridA(NN / 128, HH);   // (128, 8) = 1024 blocks x 8 waves
    vq_assign_kernel<<<gridA, 512, 0, stream>>>(
        z, cb, cb_hi, cb_lo,
        out + OFF_ZQ, out + OFF_IDX, sseP, cnts, sums);

    dim3 gridB((HH * MM) / 4);  // 2048 blocks x 4 waves (one wave per code)
    vq_update_kernel<<<gridB, 256, 0, stream>>>(
        z, cb, out + OFF_IDX, sseP,
        out + OFF_CB, out + OFF_LOSS, cnts, sums);
}

// Round 10
// 184.796 us; speedup vs baseline: 2.0012x; 2.0012x over previous
//
#include <hip/hip_runtime.h>
#include <hip/hip_bf16.h>
#include <math.h>

// Problem constants
#define BZ   8
#define DD   512
#define LL   2048
#define HH   8
#define MM   1024
#define DH   64
#define NN   (BZ * LL)               // 16384 rows per head
#define TOTAL_ELEMS (HH * NN * DH)   // 8388608

// d_out layout (floats): [z_q (8388608)] [vq_loss (1)] [indices (131072)] [codebooks (524288)]
#define OFF_ZQ   0
#define OFF_LOSS 8388608
#define OFF_IDX  8388609
#define OFF_CB   8519681

// Bucket capacity per code (avg load = 16; random-normal max ~50; overflow -> scan fallback)
#define CAP  128

// d_ws layout (bucket mode):
// [sse 64B][counts 32KB][lists ushort 2MB][cb_hi 1MB][cb_lo 1MB][zs fp32 33.5MB]
#define WSB_SSE    0
#define WSB_CNT    64
#define WSB_LST    (64 + HH * MM * 4)                         // 32,832
#define WSB_CBHI   (WSB_LST + HH * MM * CAP * 2)              // 2,129,984
#define WSB_CBLO   (WSB_CBHI + HH * MM * DH * 2)              // 3,178,560
#define WSB_ZS     (WSB_CBLO + HH * MM * DH * 2)              // 4,227,136
#define WS_NEED_BUCKET ((size_t)WSB_ZS + (size_t)HH * NN * DH * 4)   // 37,781,568

// Legacy layout (fat/thin fallback): [sse 64B][cb_hi 1MB][cb_lo 1MB][zs 33.5MB]
#define WS_PLANES_BYTE 64
#define WS_ZSPLIT_BYTE (64 + 2u * HH * MM * DH * 2)                   // 2,097,216
#define WS_NEED_FAT    (WS_ZSPLIT_BYTE + (size_t)HH * NN * DH * 4)    // ~35.7 MB

typedef __attribute__((ext_vector_type(8))) short short8;
typedef __attribute__((ext_vector_type(4))) float float4v;

__device__ __forceinline__ unsigned short f2bf(float f) {
    unsigned int u = __builtin_bit_cast(unsigned int, f);
    u += 0x7FFFu + ((u >> 16) & 1u);          // RNE
    return (unsigned short)(u >> 16);
}
__device__ __forceinline__ float bf2f(unsigned short s) {
    unsigned int u = ((unsigned int)s) << 16;
    return __builtin_bit_cast(float, u);
}

__device__ __forceinline__ void gload16(const short* g, short* l) {
    __builtin_amdgcn_global_load_lds(
        (const __attribute__((address_space(1))) unsigned int*)g,
        (__attribute__((address_space(3))) unsigned int*)l, 16, 0, 0);
}

// R19: R18 atomic-sums REVERTED (301MB write amplification, assign 296us).
// Back to measured-best R12/R16 structure (190.26us). cvt zeroes sse + counts
// (no memset node).
__global__ __launch_bounds__(256) void cvt_cb_kernel(
    const float* __restrict__ cb, short* __restrict__ hip_, short* __restrict__ lop_,
    float* __restrict__ sse, int* __restrict__ cnts)
{
    const int tid = blockIdx.x * 256 + threadIdx.x;
    if (tid < 16) sse[tid] = 0.f;                      // sse (+ scratch words)
    if (cnts && tid < HH * MM) cnts[tid] = 0;          // bucket counts
    const int c   = tid & 7;
    const int row = tid >> 3;                          // h*MM + m
    const float* __restrict__ src = cb + (size_t)row * DH + c * 8;
    short hs[8], ls[8];
#pragma unroll
    for (int j = 0; j < 8; ++j) {
        const float f = src[j];
        const unsigned short hv = f2bf(f);
        hs[j] = (short)hv;
        ls[j] = (short)f2bf(f - bf2f(hv));
    }
    const int dst = row * DH + ((c ^ (row & 7)) * 8);
    *(short8*)&hip_[dst] = *(short8*)hs;
    *(short8*)&lop_[dst] = *(short8*)ls;
}

// R12 assign internals (measured 112us) + R19 change: head-clustered XCD
// swizzle. Dispatch is x-major so xcd = (y*128+x)%8 = x%8; mapping h = x&7
// gives each XCD exactly one head's codebook state (512KB: hi+lo planes +
// fp32 cb) -> fully L2-resident staging instead of 6MB/XCD thrash to L3.
// Bijection: h = x&7, bx = (x>>3) + 16*y  (x in [0,128), y in [0,8)).
__global__ __launch_bounds__(512) void vq_assign_kernel(
    const float* __restrict__ z,          // [B, D, L]
    const float* __restrict__ cb,         // [H, M, DH] fp32 (rescreen/epilogue)
    const short* __restrict__ cb_hi,      // bf16 hi, swizzled
    const short* __restrict__ cb_lo,      // bf16 lo, swizzled
    float* __restrict__ zq_out,
    float* __restrict__ idx_out,
    float* __restrict__ sse,
    float* __restrict__ zs,               // [H, N, DH] or null
    int*   __restrict__ cnts,             // [H*M] or null
    unsigned short* __restrict__ lists)   // [H*M][CAP] or null
{
    __shared__ __align__(16) short hi_lds[2][64 * DH];   // 2 x 8 KB
    __shared__ __align__(16) short lo_lds[2][64 * DH];   // 2 x 8 KB
    __shared__ float blk_err[8];

    const int t    = threadIdx.x;
    // R19 swizzle: one head per XCD.
    const int h    = blockIdx.x & 7;
    const int bx   = (blockIdx.x >> 3) + 16 * blockIdx.y;
    const int lane = t & 63;
    const int g    = lane >> 4;          // quad 0..3
    const int nloc = lane & 15;
    const int w    = t >> 6;             // wave 0..7

    // This lane's z row (16 rows per wave, 128 per block); 4 quads share a row.
    const int r = bx * 128 + w * 16 + nloc;
    const int b = r >> 11;
    const int l = r & (LL - 1);
    const float* __restrict__ zbase = z + ((size_t)(b * DD + h * DH) * LL + l);

    // B-fragment z values: zv[j] <-> k=g*8+j, zv[8+j] <-> k=32+g*8+j.
    float zv[16] __attribute__((aligned(16)));
#pragma unroll
    for (int j = 0; j < 8; ++j) zv[j]     = zbase[(size_t)(g * 8 + j) * LL];
#pragma unroll
    for (int j = 0; j < 8; ++j) zv[8 + j] = zbase[(size_t)(32 + g * 8 + j) * LL];

    // Optional: write this row's chunk to z_split [H, N, 64] for the fast B gather.
    if (zs) {
        float* __restrict__ zr_ = zs + ((size_t)h * NN + r) * DH;
        *(float4*)&zr_[g * 8]          = *(const float4*)&zv[0];
        *(float4*)&zr_[g * 8 + 4]      = *(const float4*)&zv[4];
        *(float4*)&zr_[32 + g * 8]     = *(const float4*)&zv[8];
        *(float4*)&zr_[32 + g * 8 + 4] = *(const float4*)&zv[12];
    }

    short bh[16], bl[16];
#pragma unroll
    for (int j = 0; j < 16; ++j) {
        const unsigned short hv = f2bf(zv[j]);
        bh[j] = (short)hv;
        bl[j] = (short)f2bf(zv[j] - bf2f(hv));
    }
    const short8 Bh0 = *(short8*)&bh[0], Bh1 = *(short8*)&bh[8];
    const short8 Bl0 = *(short8*)&bl[0], Bl1 = *(short8*)&bl[8];

    const short* __restrict__ gh = cb_hi + (size_t)h * MM * DH;
    const short* __restrict__ gl = cb_lo + (size_t)h * MM * DH;

    // Stage one 64-row tile (8 KB hi + 8 KB lo): 512 threads x 16B each plane.
    auto stage = [&](int mt, int buf) {
        const short* sh = gh + (size_t)mt * 64 * DH;
        const short* sl = gl + (size_t)mt * 64 * DH;
        gload16(sh + t * 8, &hi_lds[buf][t * 8]);
        gload16(sl + t * 8, &lo_lds[buf][t * 8]);
    };

    stage(0, 0);

    // 4 independent top-2 chains (one per s class), merged at the end.
    float b1c[4], b2c[4];
    int   i1c[4], i2c[4];
#pragma unroll
    for (int s = 0; s < 4; ++s) { b1c[s] = -1e30f; b2c[s] = -1e30f; i1c[s] = 0; i2c[s] = 0; }

    const int sw8 = nloc & 7;

    for (int mt = 0; mt < MM / 64; ++mt) {
        __syncthreads();                       // vmcnt(0) drains exactly tile mt's DMA
        if (mt + 1 < MM / 64) stage(mt + 1, (mt + 1) & 1);
        const int buf = mt & 1;

#pragma unroll
        for (int s = 0; s < 4; ++s) {
            const short* hrow = &hi_lds[buf][(s * 16 + nloc) * DH];
            const short* lrow = &lo_lds[buf][(s * 16 + nloc) * DH];
            const short8 Ah0 = *(const short8*)&hrow[((g)     ^ sw8) * 8];
            const short8 Ah1 = *(const short8*)&hrow[((g + 4) ^ sw8) * 8];
            const short8 Al0 = *(const short8*)&lrow[((g)     ^ sw8) * 8];
            const short8 Al1 = *(const short8*)&lrow[((g + 4) ^ sw8) * 8];

            float4v acc = {0.f, 0.f, 0.f, 0.f};
            acc = __builtin_amdgcn_mfma_f32_16x16x32_bf16(Ah0, Bh0, acc, 0, 0, 0);
            acc = __builtin_amdgcn_mfma_f32_16x16x32_bf16(Ah1, Bh1, acc, 0, 0, 0);
            acc = __builtin_amdgcn_mfma_f32_16x16x32_bf16(Ah0, Bl0, acc, 0, 0, 0);
            acc = __builtin_amdgcn_mfma_f32_16x16x32_bf16(Ah1, Bl1, acc, 0, 0, 0);
            acc = __builtin_amdgcn_mfma_f32_16x16x32_bf16(Al0, Bh0, acc, 0, 0, 0);
            acc = __builtin_amdgcn_mfma_f32_16x16x32_bf16(Al1, Bh1, acc, 0, 0, 0);

            const int mbase = mt * 64 + s * 16 + g * 4;
#pragma unroll
            for (int reg = 0; reg < 4; ++reg) {
                const float v = acc[reg];
                const int   m = mbase + reg;
                // top-2 of {v, b1, b2}: b1' = max(v,b1); b2' = med3(v,b1,b2).
                const bool gt1 = v > b1c[s];
                const bool gt2 = v > b2c[s];
                b2c[s] = __builtin_amdgcn_fmed3f(v, b1c[s], b2c[s]);
                i2c[s] = gt1 ? i1c[s] : (gt2 ? m : i2c[s]);
                b1c[s] = fmaxf(v, b1c[s]);
                i1c[s] = gt1 ? m : i1c[s];
            }
        }
    }

    // Merge the 4 chains into one top-2 (value desc, index-asc tie-break).
    float b1 = b1c[0], b2 = b2c[0];
    int   i1 = i1c[0], i2 = i2c[0];
#pragma unroll
    for (int s = 1; s < 4; ++s) {
        const float ob1 = b1c[s], ob2 = b2c[s];
        const int   oi1 = i1c[s], oi2 = i2c[s];
        const bool agt = (b1 > ob1) || (b1 == ob1 && i1 < oi1);
        const float w1 = agt ? b1 : ob1;  const int wi1 = agt ? i1 : oi1;
        const float l1 = agt ? ob1 : b1;  const int li1 = agt ? oi1 : i1;
        const float w2 = agt ? b2 : ob2;  const int wi2 = agt ? i2 : oi2;
        const bool sgt = (l1 > w2) || (l1 == w2 && li1 < wi2);
        b1 = w1;  i1 = wi1;
        b2 = sgt ? l1 : w2;  i2 = sgt ? li1 : wi2;
    }

    // Merge top-2 across the 4 quads holding the same row.
#pragma unroll
    for (int off = 16; off <= 32; off <<= 1) {
        float ob1 = __shfl_xor(b1, off, 64);
        int   oi1 = __shfl_xor(i1, off, 64);
        float ob2 = __shfl_xor(b2, off, 64);
        int   oi2 = __shfl_xor(i2, off, 64);
        const bool agt = (b1 > ob1) || (b1 == ob1 && i1 < oi1);
        const float w1  = agt ? b1 : ob1;  const int wi1 = agt ? i1 : oi1;
        const float l1  = agt ? ob1 : b1;  const int li1 = agt ? oi1 : i1;
        const float w2  = agt ? b2 : ob2;  const int wi2 = agt ? i2 : oi2;
        const bool sgt = (l1 > w2) || (l1 == w2 && li1 < wi2);
        b1 = w1;  i1 = wi1;
        b2 = sgt ? l1 : w2;  i2 = sgt ? li1 : wi2;
    }

    // Exact fp64 rescreen of the two candidates (global fp32), reusing zv.
    const float* __restrict__ cbh = cb + (size_t)h * MM * DH;
    const float* __restrict__ c1  = cbh + (size_t)i1 * DH;
    const float* __restrict__ c2  = cbh + (size_t)i2 * DH;
    double d1 = 0.0, d2 = 0.0;
#pragma unroll
    for (int j = 0; j < 8; ++j) {
        const int k0 = g * 8 + j, k1 = 32 + g * 8 + j;
        d1 = fma((double)zv[j],     (double)c1[k0], d1);
        d1 = fma((double)zv[8 + j], (double)c1[k1], d1);
        d2 = fma((double)zv[j],     (double)c2[k0], d2);
        d2 = fma((double)zv[8 + j], (double)c2[k1], d2);
    }
    d1 += __shfl_xor(d1, 16, 64);  d1 += __shfl_xor(d1, 32, 64);
    d2 += __shfl_xor(d2, 16, 64);  d2 += __shfl_xor(d2, 32, 64);
    const int best = (d2 > d1 || (d2 == d1 && i2 < i1)) ? i2 : i1;

    // Epilogue: quantized row, squared error, idx, bucket entry.
    const float* __restrict__ cq  = cbh + (size_t)best * DH;
    float* __restrict__ zqp  = zq_out + ((size_t)(b * DD + h * DH) * LL + l);
    float err = 0.f;
#pragma unroll
    for (int j = 0; j < 8; ++j) {
        const int k0 = g * 8 + j, k1 = 32 + g * 8 + j;
        const float q0 = cq[k0], q1 = cq[k1];
        zqp[(size_t)k0 * LL] = q0;
        zqp[(size_t)k1 * LL] = q1;
        const float e0 = zv[j] - q0, e1 = zv[8 + j] - q1;
        err = fmaf(e0, e0, err);
        err = fmaf(e1, e1, err);
    }
    if (g == 0) {
        idx_out[((size_t)b * HH + h) * LL + l] = (float)best;
        if (cnts) {
            const int code = h * MM + best;
            const int slot = atomicAdd(&cnts[code], 1);
            if (slot < CAP) lists[(size_t)code * CAP + slot] = (unsigned short)r;
        }
    }
#pragma unroll
    for (int off = 32; off; off >>= 1) err += __shfl_xor(err, off, 64);
    // Two-stage sse reduction (one atomic per block).
    if (lane == 0) blk_err[w] = err;
    __syncthreads();
    if (t == 0) {
        float s = 0.f;
#pragma unroll
        for (int i = 0; i < 8; ++i) s += blk_err[i];
        atomicAdd(sse, s);
    }
}

// One wave per (h,m) code. Bucket fast path — read cnt + <=CAP row ids,
// gather 256B-contiguous zs rows directly. Scan fallback kept for cnt>CAP or
// thin workspace.
__global__ __launch_bounds__(256) void vq_update_kernel(
    const float* __restrict__ z,        // [B, D, L]
    const float* __restrict__ zs,       // [H, N, DH] or null
    const float* __restrict__ cb,       // [H, M, DH]
    const float* __restrict__ idx,      // [B, H, L] as float
    const float* __restrict__ sse,
    float* __restrict__ cb_out,
    float* __restrict__ loss_out,
    const int* __restrict__ cnts,       // [H*M] or null
    const unsigned short* __restrict__ lists)  // [H*M][CAP] or null
{
    if (blockIdx.x == 0 && threadIdx.x == 0) {
        loss_out[0] = 1.25f * sse[0] / (float)TOTAL_ELEMS;
    }
    const int row  = blockIdx.x * 4 + (threadIdx.x >> 6);   // h*MM + m
    const int lane = threadIdx.x & 63;
    const int h    = row >> 10;
    const int m    = row & (MM - 1);
    const float fm = (float)m;

    float acc = 0.f;
    int   cnt = 0;
    bool  fast = false;
    if (cnts) { cnt = cnts[row]; fast = (cnt <= CAP); }

    if (fast) {
        const unsigned short* __restrict__ lst = lists + (size_t)row * CAP;
        const float* __restrict__ zsh = zs + ((size_t)h * NN) * DH + lane;
        float a0 = 0.f, a1 = 0.f, a2 = 0.f, a3 = 0.f;
        int i = 0;
        for (; i + 4 <= cnt; i += 4) {
            const int n0 = lst[i], n1 = lst[i + 1], n2 = lst[i + 2], n3 = lst[i + 3];
            a0 += zsh[(size_t)n0 * DH];
            a1 += zsh[(size_t)n1 * DH];
            a2 += zsh[(size_t)n2 * DH];
            a3 += zsh[(size_t)n3 * DH];
        }
        for (; i < cnt; ++i) acc += zsh[(size_t)lst[i] * DH];
        acc += (a0 + a1) + (a2 + a3);
    } else {
        cnt = 0;
#pragma unroll 1
        for (int b = 0; b < BZ; ++b) {
            const float* __restrict__ ip  = idx + ((size_t)(b * HH + h)) * LL;
            const float* __restrict__ zb  = z + ((size_t)(b * DD + h * DH + lane)) * LL;
            const float* __restrict__ zsb = zs ? (zs + ((size_t)h * NN + (size_t)b * LL) * DH + lane)
                                              : (const float*)0;
            float4 cur = *(const float4*)(ip + lane * 4);
#pragma unroll 1
            for (int it = 0; it < LL / 256; ++it) {
                float4 nxt = cur;
                if (it + 1 < LL / 256)
                    nxt = *(const float4*)(ip + (it + 1) * 256 + lane * 4);
#pragma unroll
                for (int j = 0; j < 4; ++j) {
                    const float ivj = (&cur.x)[j];
                    unsigned long long mask = __ballot(ivj == fm);
                    cnt += (int)__popcll(mask);
                    while (mask) {
                        const int src = (int)__ffsll((long long)mask) - 1;
                        mask &= mask - 1;
                        const int l = it * 256 + src * 4 + j;
                        acc += zsb ? zsb[(size_t)l * DH]
                                   : zb[l];
                    }
                }
                cur = nxt;
            }
        }
    }

    const float cf   = (float)cnt;
    const float c    = cb[(size_t)row * DH + lane];
    const float mean = acc / fmaxf(cf, 1.0f);

    float dot = mean * c;
    float nl  = mean * mean;
    float nh  = c * c;
#pragma unroll
    for (int off = 32; off; off >>= 1) {
        dot += __shfl_xor(dot, off, 64);
        nl  += __shfl_xor(nl,  off, 64);
        nh  += __shfl_xor(nh,  off, 64);
    }

    float cosv = dot / fmaxf(sqrtf(nl) * sqrtf(nh), 1e-8f);
    cosv = fminf(fmaxf(cosv, -0.9999999f), 0.9999999f);
    const float omega = acosf(cosv);
    const float so    = sinf(omega);
    float outv = (mean * sinf(0.01f * omega) + c * sinf(0.99f * omega)) / so;

    float ms = outv * outv;
#pragma unroll
    for (int off = 32; off; off >>= 1) ms += __shfl_xor(ms, off, 64);
    ms = ms * (1.0f / (float)DH) + 1.1920929e-07f;
    const float normed = outv / sqrtf(ms);

    cb_out[(size_t)row * DH + lane] = (cnt > 0) ? normed : c;
}

extern "C" void kernel_launch(void* const* d_in, const int* in_sizes, int n_in,
                              void* d_out, int out_size, void* d_ws, size_t ws_size,
                              hipStream_t stream) {
    const float* z  = (const float*)d_in[0];
    const float* cb = (const float*)d_in[1];
    float* out = (float*)d_out;

    const bool bucket = ws_size >= WS_NEED_BUCKET;
    const bool fat    = ws_size >= WS_NEED_FAT;

    short *cb_hi, *cb_lo;
    float *zs = 0;
    int   *cnts = 0;
    unsigned short *lists = 0;

    if (bucket) {
        cnts  = (int*)((char*)d_ws + WSB_CNT);
        lists = (unsigned short*)((char*)d_ws + WSB_LST);
        cb_hi = (short*)((char*)d_ws + WSB_CBHI);
        cb_lo = (short*)((char*)d_ws + WSB_CBLO);
        zs    = (float*)((char*)d_ws + WSB_ZS);
    } else {
        cb_hi = (short*)((char*)d_ws + WS_PLANES_BYTE);
        cb_lo = cb_hi + (size_t)HH * MM * DH;
        zs    = fat ? (float*)((char*)d_ws + WS_ZSPLIT_BYTE) : (float*)0;
    }

    // cvt zeroes sse + counts (no memset node).
    cvt_cb_kernel<<<(HH * MM * DH / 8) / 256, 256, 0, stream>>>(
        cb, cb_hi, cb_lo, (float*)d_ws, cnts);

    dim3 gridA(NN / 128, HH);   // (128, 8) = 1024 blocks x 8 waves
    vq_assign_kernel<<<gridA, 512, 0, stream>>>(
        z, cb, cb_hi, cb_lo,
        out + OFF_ZQ, out + OFF_IDX, (float*)d_ws, zs, cnts, lists);

    dim3 gridB((HH * MM) / 4);  // 2048 blocks x 4 waves (one wave per code)
    vq_update_kernel<<<gridB, 256, 0, stream>>>(
        z, zs, cb, out + OFF_IDX, (float*)d_ws,
        out + OFF_CB, out + OFF_LOSS, cnts, lists);
}